// Round 2
// baseline (932.122 us; speedup 1.0000x reference)
//
#include <hip/hip_runtime.h>
#include <hip/hip_bf16.h>
#include <cstdint>
#include <cstddef>

// Problem dims
#define BDIM 8192
#define D1 1024
#define D2 1024
#define HDIM 4096

// GEMM tile
#define BM 128
#define BN 128
#define BK 64

typedef __attribute__((ext_vector_type(8))) short short8;
typedef __attribute__((ext_vector_type(4))) float f32x4;

__device__ inline void async_load16(const void* g, void* l) {
  __builtin_amdgcn_global_load_lds(
      (const __attribute__((address_space(1))) void*)g,
      (__attribute__((address_space(3))) void*)l,
      16 /*bytes*/, 0 /*offset*/, 0 /*aux*/);
}

__device__ inline unsigned short f2bf(float f) {
  union { float f; uint32_t u; } v; v.f = f;
  uint32_t u = v.u;
  uint32_t r = u + 0x7FFFu + ((u >> 16) & 1u);  // RNE
  return (unsigned short)(r >> 16);
}

// ---------------------------------------------------------------------------
// GEMM: C[M,N] = A[M,K] @ B^T[N,K]^T (+bias), A/B bf16 (as ushort), acc fp32.
// mode 0: ReLU -> bf16 out.  mode 1: fp32 out (+bias, no relu).
// grid: (N/BN, M/BM, 2); z picks the {s,t} pointer set.
// ---------------------------------------------------------------------------
__global__ __launch_bounds__(256, 2)
void gemm_bt(const unsigned short* __restrict__ A0,
             const unsigned short* __restrict__ A1,
             const unsigned short* __restrict__ B0,
             const unsigned short* __restrict__ B1,
             const float* __restrict__ bias0,
             const float* __restrict__ bias1,
             void* __restrict__ C0v, void* __restrict__ C1v,
             int M, int N, int K, int mode) {
  const unsigned short* A = blockIdx.z ? A1 : A0;
  const unsigned short* B = blockIdx.z ? B1 : B0;
  const float* bias = blockIdx.z ? bias1 : bias0;

  __shared__ __align__(16) unsigned short lsA[BM * BK];
  __shared__ __align__(16) unsigned short lsB[BN * BK];

  const int tid  = threadIdx.x;
  const int wave = tid >> 6;
  const int lane = tid & 63;
  const int quad = lane >> 4;
  const int l15  = lane & 15;

  const int m0 = blockIdx.y * BM;
  const int n0 = blockIdx.x * BN;
  const int wrow = (wave >> 1) * 64;   // wave tile 64x64, 2x2 wave grid
  const int wcol = (wave & 1) * 64;

  f32x4 acc[4][4] = {};

  for (int k0 = 0; k0 < K; k0 += BK) {
    __syncthreads();  // previous tile fully consumed
    // Stage A and B tiles: 1024 granules (16B) each; 256 thr x 4 iters.
    // XOR swizzle: phys granule s holds logical (row = s>>3, kg = (s&7)^(row&7)).
#pragma unroll
    for (int i = 0; i < 4; ++i) {
      int s   = (wave * 4 + i) * 64 + lane;
      int row = s >> 3;
      int kg  = (s & 7) ^ (row & 7);
      const unsigned short* ga = A + (long)(m0 + row) * K + k0 + kg * 8;
      async_load16(ga, &lsA[(wave * 4 + i) * 512]);
      const unsigned short* gb = B + (long)(n0 + row) * K + k0 + kg * 8;
      async_load16(gb, &lsB[(wave * 4 + i) * 512]);
    }
    __syncthreads();  // compiler drains vmcnt before barrier

#pragma unroll
    for (int ks = 0; ks < 2; ++ks) {  // two K=32 MFMA steps per BK=64 tile
      short8 af[4], bfr[4];
      const int kg = ks * 4 + quad;
#pragma unroll
      for (int t = 0; t < 4; ++t) {
        int row = wrow + t * 16 + l15;
        int pa  = row * 8 + (kg ^ (row & 7));
        af[t] = *(const short8*)&lsA[pa * 8];
        int col = wcol + t * 16 + l15;
        int pb  = col * 8 + (kg ^ (col & 7));
        bfr[t] = *(const short8*)&lsB[pb * 8];
      }
#pragma unroll
      for (int mt = 0; mt < 4; ++mt)
#pragma unroll
        for (int nt = 0; nt < 4; ++nt)
          acc[mt][nt] = __builtin_amdgcn_mfma_f32_16x16x32_bf16(
              af[mt], bfr[nt], acc[mt][nt], 0, 0, 0);
    }
  }

  // Epilogue. C/D layout: col = lane&15, row = quad*4 + reg  [m89/m91 verified]
  if (mode == 0) {
    unsigned short* C = blockIdx.z ? (unsigned short*)C1v : (unsigned short*)C0v;
#pragma unroll
    for (int mt = 0; mt < 4; ++mt)
#pragma unroll
      for (int nt = 0; nt < 4; ++nt) {
        int col = n0 + wcol + nt * 16 + l15;
        float bv = bias[col];
#pragma unroll
        for (int r = 0; r < 4; ++r) {
          int row = m0 + wrow + mt * 16 + quad * 4 + r;
          float v = acc[mt][nt][r] + bv;
          v = v > 0.f ? v : 0.f;
          C[(long)row * N + col] = f2bf(v);
        }
      }
  } else {
    float* C = blockIdx.z ? (float*)C1v : (float*)C0v;
#pragma unroll
    for (int mt = 0; mt < 4; ++mt)
#pragma unroll
      for (int nt = 0; nt < 4; ++nt) {
        int col = n0 + wcol + nt * 16 + l15;
        float bv = bias[col];
#pragma unroll
        for (int r = 0; r < 4; ++r) {
          int row = m0 + wrow + mt * 16 + quad * 4 + r;
          C[(long)row * N + col] = acc[mt][nt][r] + bv;
        }
      }
  }
}

// ---------------------------------------------------------------------------
// Transpose + fp32->bf16 cast: in[R,C] fp32 -> out[C,R] bf16(ushort).
// grid: (C/32, R/32), block 256.
// ---------------------------------------------------------------------------
__global__ __launch_bounds__(256)
void transpose_cast(const float* __restrict__ in, unsigned short* __restrict__ out,
                    int R, int C) {
  __shared__ float tile[32][33];
  const int bx = blockIdx.x * 32;  // col base (input)
  const int by = blockIdx.y * 32;  // row base (input)
  const int tx = threadIdx.x & 31;
  const int ty = threadIdx.x >> 5;  // 0..7
  for (int j = ty; j < 32; j += 8)
    tile[j][tx] = in[(long)(by + j) * C + bx + tx];
  __syncthreads();
  for (int j = ty; j < 32; j += 8)
    out[(long)(bx + j) * R + by + tx] = f2bf(tile[tx][j]);
}

// x (B, 2048) fp32 -> x2 bf16 packed (B, 1024)
__global__ __launch_bounds__(256)
void cast_x2(const float* __restrict__ x, unsigned short* __restrict__ x2b) {
  long i = (long)blockIdx.x * 256 + threadIdx.x;  // over B*D1
  long row = i >> 10, col = i & 1023;
  x2b[i] = f2bf(x[row * (D1 + D2) + D2 + col]);
}

// ---------------------------------------------------------------------------
// Coupling elementwise, chunk-aware. Local row r = blockIdx.x indexes
// s_lin/t_lin (chunk-local); global row g = moff + r indexes x / y_out /
// y_bf / ldp / ld_out.
// stage 0: y1 = x1*exp(tanh(s)) + t -> d_out cols [0,D1), y1 bf16 -> y_bf,
//          rowsum(tanh(s)) -> ld_partial.
// stage 1: y2 = x2*exp(tanh(s)) + t -> d_out cols [D1,2*D1),
//          ld_out = ld_partial + rowsum.
// ---------------------------------------------------------------------------
__global__ __launch_bounds__(256)
void coupling(const float* __restrict__ s_lin, const float* __restrict__ t_lin,
              const float* __restrict__ x, float* __restrict__ y_out,
              unsigned short* __restrict__ y_bf, float* __restrict__ ld_partial,
              float* __restrict__ ld_out, int stage, int moff) {
  const int r = blockIdx.x;
  const long g = moff + r;
  const int tid = threadIdx.x;
  const int off = stage ? D1 : 0;
  float part = 0.f;
  for (int c = tid; c < D1; c += 256) {
    float sv = tanhf(s_lin[(long)r * D1 + c]);
    part += sv;
    float y = x[g * (D1 + D2) + off + c] * expf(sv) + t_lin[(long)r * D1 + c];
    y_out[g * (D1 + D2) + off + c] = y;
    if (y_bf) y_bf[g * D1 + c] = f2bf(y);
  }
  for (int o = 32; o > 0; o >>= 1) part += __shfl_down(part, o, 64);
  __shared__ float red[4];
  if ((tid & 63) == 0) red[tid >> 6] = part;
  __syncthreads();
  if (tid == 0) {
    float tot = red[0] + red[1] + red[2] + red[3];
    if (stage == 0) ld_partial[g] = tot;
    else            ld_out[g] = ld_partial[g] + tot;
  }
}

// ---------------------------------------------------------------------------
extern "C" void kernel_launch(void* const* d_in, const int* in_sizes, int n_in,
                              void* d_out, int out_size, void* d_ws, size_t ws_size,
                              hipStream_t stream) {
  const float* x     = (const float*)d_in[0];
  const float* s1_W1 = (const float*)d_in[1];
  const float* s1_b1 = (const float*)d_in[2];
  const float* s1_W2 = (const float*)d_in[3];
  const float* s1_b2 = (const float*)d_in[4];
  const float* t1_W1 = (const float*)d_in[5];
  const float* t1_b1 = (const float*)d_in[6];
  const float* t1_W2 = (const float*)d_in[7];
  const float* t1_b2 = (const float*)d_in[8];
  const float* s2_W1 = (const float*)d_in[9];
  const float* s2_b1 = (const float*)d_in[10];
  const float* s2_W2 = (const float*)d_in[11];
  const float* s2_b2 = (const float*)d_in[12];
  const float* t2_W1 = (const float*)d_in[13];
  const float* t2_b1 = (const float*)d_in[14];
  const float* t2_W2 = (const float*)d_in[15];
  const float* t2_b2 = (const float*)d_in[16];

  // ---- workspace budget: chunk the (row-independent) batch to fit ws ----
  const size_t MB = 1024UL * 1024UL;
  // fixed: ldp 32KB @0 (pad to 1MB) | w1t 4x8MB @1MB | w2t 4x8MB @33MB
  //        | x2b/y1b (aliased) 16MB @65MB | per-chunk h/slin/tlin @81MB
  int NC = 32;
  {
    const int cand[6] = {1, 2, 4, 8, 16, 32};
    for (int i = 0; i < 6; ++i) {
      size_t need = 81 * MB + (192 * MB) / (size_t)cand[i];
      if (need <= ws_size) { NC = cand[i]; break; }
    }
  }
  const int Mrows = BDIM / NC;

  char* ws = (char*)d_ws;
  float* ldp = (float*)(ws + 0);                                 // 32KB
  unsigned short* w1t[4], * w2t[4];
  for (int i = 0; i < 4; ++i) {
    w1t[i] = (unsigned short*)(ws + (1 + 8 * (size_t)i) * MB);   // 4x8MB
    w2t[i] = (unsigned short*)(ws + (33 + 8 * (size_t)i) * MB);  // 4x8MB
  }
  unsigned short* xyb = (unsigned short*)(ws + 65 * MB);         // 16MB, x2b & y1b
  size_t hbytes = (size_t)Mrows * HDIM * 2;                      // 64MB/NC
  size_t sbytes = (size_t)Mrows * D1 * 4;                        // 32MB/NC
  unsigned short* h_s = (unsigned short*)(ws + 81 * MB);
  unsigned short* h_t = (unsigned short*)(ws + 81 * MB + hbytes);
  float* slin = (float*)(ws + 81 * MB + 2 * hbytes);
  float* tlin = (float*)(ws + 81 * MB + 2 * hbytes + sbytes);

  float* y_out  = (float*)d_out;                 // (B, 2048)
  float* ld_out = (float*)d_out + (long)BDIM * (D1 + D2);

  // --- prep: casts + weight transposes (full batch, once) ---
  cast_x2<<<(BDIM * D1) / 256, 256, 0, stream>>>(x, xyb);
  // W1: (1024, 4096) -> (4096, 1024)
  transpose_cast<<<dim3(HDIM / 32, D1 / 32), 256, 0, stream>>>(s1_W1, w1t[0], D1, HDIM);
  transpose_cast<<<dim3(HDIM / 32, D1 / 32), 256, 0, stream>>>(t1_W1, w1t[1], D1, HDIM);
  transpose_cast<<<dim3(HDIM / 32, D1 / 32), 256, 0, stream>>>(s2_W1, w1t[2], D1, HDIM);
  transpose_cast<<<dim3(HDIM / 32, D1 / 32), 256, 0, stream>>>(t2_W1, w1t[3], D1, HDIM);
  // W2: (4096, 1024) -> (1024, 4096)
  transpose_cast<<<dim3(D1 / 32, HDIM / 32), 256, 0, stream>>>(s1_W2, w2t[0], HDIM, D1);
  transpose_cast<<<dim3(D1 / 32, HDIM / 32), 256, 0, stream>>>(t1_W2, w2t[1], HDIM, D1);
  transpose_cast<<<dim3(D1 / 32, HDIM / 32), 256, 0, stream>>>(s2_W2, w2t[2], HDIM, D1);
  transpose_cast<<<dim3(D1 / 32, HDIM / 32), 256, 0, stream>>>(t2_W2, w2t[3], HDIM, D1);

  // --- per-chunk pipeline (rows are independent end-to-end) ---
  for (int c = 0; c < NC; ++c) {
    const int moff = c * Mrows;
    const unsigned short* xA = xyb + (size_t)moff * D1;  // x2 rows (bf16)

    // stage 1: MLPs of x2 (s1 & t1)
    gemm_bt<<<dim3(HDIM / BN, Mrows / BM, 2), 256, 0, stream>>>(
        xA, xA, w1t[0], w1t[1], s1_b1, t1_b1, h_s, h_t, Mrows, HDIM, D1, 0);
    gemm_bt<<<dim3(D1 / BN, Mrows / BM, 2), 256, 0, stream>>>(
        h_s, h_t, w2t[0], w2t[1], s1_b2, t1_b2, slin, tlin, Mrows, D1, HDIM, 1);
    coupling<<<Mrows, 256, 0, stream>>>(slin, tlin, x, y_out, xyb, ldp, nullptr, 0, moff);

    // stage 2: MLPs of y1 (s2 & t2); y1 bf16 aliases x2b rows (already dead)
    const unsigned short* yA = xyb + (size_t)moff * D1;
    gemm_bt<<<dim3(HDIM / BN, Mrows / BM, 2), 256, 0, stream>>>(
        yA, yA, w1t[2], w1t[3], s2_b1, t2_b1, h_s, h_t, Mrows, HDIM, D1, 0);
    gemm_bt<<<dim3(D1 / BN, Mrows / BM, 2), 256, 0, stream>>>(
        h_s, h_t, w2t[2], w2t[3], s2_b2, t2_b2, slin, tlin, Mrows, D1, HDIM, 1);
    coupling<<<Mrows, 256, 0, stream>>>(slin, tlin, x, y_out, nullptr, ldp, ld_out, 1, moff);
  }
}

// Round 3
// 913.169 us; speedup vs baseline: 1.0208x; 1.0208x over previous
//
#include <hip/hip_runtime.h>
#include <hip/hip_bf16.h>
#include <cstdint>
#include <cstddef>

// Problem dims
#define BDIM 8192
#define D1 1024
#define HDIM 4096

// GEMM tile
#define BM 128
#define BN 128
#define BK 64

typedef __attribute__((ext_vector_type(8))) short short8;
typedef __attribute__((ext_vector_type(4))) float f32x4;

__device__ inline void async_load16(const void* g, void* l) {
  __builtin_amdgcn_global_load_lds(
      (const __attribute__((address_space(1))) void*)g,
      (__attribute__((address_space(3))) void*)l,
      16 /*bytes*/, 0 /*offset*/, 0 /*aux*/);
}

__device__ inline unsigned short f2bf(float f) {
  union { float f; uint32_t u; } v; v.f = f;
  uint32_t u = v.u;
  uint32_t r = u + 0x7FFFu + ((u >> 16) & 1u);  // RNE
  return (unsigned short)(r >> 16);
}

// ---------------------------------------------------------------------------
// Layer-1 fused: Cs = relu(A@Ws^T+bs), Ct = relu(A@Wt^T+bt), bf16 out.
// A[M,1024] bf16 (SHARED between s and t paths), Bs/Bt[4096,1024] bf16 (N-major).
// grid: (4096/BN, M/BM). K=1024, N=4096 hardcoded.
// ---------------------------------------------------------------------------
__global__ __launch_bounds__(256, 2)
void gemm1_fused(const unsigned short* __restrict__ A,
                 const unsigned short* __restrict__ Bs,
                 const unsigned short* __restrict__ Bt,
                 const float* __restrict__ bias_s,
                 const float* __restrict__ bias_t,
                 unsigned short* __restrict__ Cs,
                 unsigned short* __restrict__ Ct) {
  const int K = 1024, N = 4096;
  __shared__ __align__(16) unsigned short lsA[BM * BK];
  __shared__ __align__(16) unsigned short lsS[BN * BK];
  __shared__ __align__(16) unsigned short lsT[BN * BK];

  const int tid  = threadIdx.x;
  const int wave = tid >> 6;
  const int lane = tid & 63;
  const int quad = lane >> 4;
  const int l15  = lane & 15;
  const int m0 = blockIdx.y * BM;
  const int n0 = blockIdx.x * BN;
  const int wrow = (wave >> 1) * 64;
  const int wcol = (wave & 1) * 64;

  f32x4 accS[4][4] = {};
  f32x4 accT[4][4] = {};

  for (int k0 = 0; k0 < K; k0 += BK) {
    __syncthreads();
#pragma unroll
    for (int i = 0; i < 4; ++i) {
      int s   = (wave * 4 + i) * 64 + lane;
      int row = s >> 3;
      int kg  = (s & 7) ^ (row & 7);
      async_load16(A  + (long)(m0 + row) * K + k0 + kg * 8, &lsA[(wave * 4 + i) * 512]);
      async_load16(Bs + (long)(n0 + row) * K + k0 + kg * 8, &lsS[(wave * 4 + i) * 512]);
      async_load16(Bt + (long)(n0 + row) * K + k0 + kg * 8, &lsT[(wave * 4 + i) * 512]);
    }
    __syncthreads();

#pragma unroll
    for (int ks = 0; ks < 2; ++ks) {
      short8 af[4], bs[4], bt[4];
      const int kg = ks * 4 + quad;
#pragma unroll
      for (int t = 0; t < 4; ++t) {
        int row = wrow + t * 16 + l15;
        af[t] = *(const short8*)&lsA[(row * 8 + (kg ^ (row & 7))) * 8];
        int col = wcol + t * 16 + l15;
        int pb  = col * 8 + (kg ^ (col & 7));
        bs[t] = *(const short8*)&lsS[pb * 8];
        bt[t] = *(const short8*)&lsT[pb * 8];
      }
#pragma unroll
      for (int mt = 0; mt < 4; ++mt)
#pragma unroll
        for (int nt = 0; nt < 4; ++nt) {
          accS[mt][nt] = __builtin_amdgcn_mfma_f32_16x16x32_bf16(
              af[mt], bs[nt], accS[mt][nt], 0, 0, 0);
          accT[mt][nt] = __builtin_amdgcn_mfma_f32_16x16x32_bf16(
              af[mt], bt[nt], accT[mt][nt], 0, 0, 0);
        }
    }
  }

  // Epilogue: bias + relu + bf16. C/D layout: col=lane&15, row=quad*4+reg.
#pragma unroll
  for (int nt = 0; nt < 4; ++nt) {
    int col = n0 + wcol + nt * 16 + l15;
    float bvs = bias_s[col], bvt = bias_t[col];
#pragma unroll
    for (int mt = 0; mt < 4; ++mt)
#pragma unroll
      for (int r = 0; r < 4; ++r) {
        long row = m0 + wrow + mt * 16 + quad * 4 + r;
        float vs = accS[mt][nt][r] + bvs;
        float vt = accT[mt][nt][r] + bvt;
        Cs[row * N + col] = f2bf(vs > 0.f ? vs : 0.f);
        Ct[row * N + col] = f2bf(vt > 0.f ? vt : 0.f);
      }
  }
}

// ---------------------------------------------------------------------------
// Layer-2 fused + coupling: s = As@Ws^T+bs, t = At@Wt^T+bt (K=4096, N=1024),
// then sv=tanh(s); y = x[:,off+c]*exp(sv) + t -> y_out[:,off+c];
// optionally y bf16 -> y_bf; rowsum(sv) atomically into ld_out.
// grid: (1024/BN, M/BM). moff = global row offset of this chunk.
// ---------------------------------------------------------------------------
__global__ __launch_bounds__(256, 2)
void gemm2_fused(const unsigned short* __restrict__ As,
                 const unsigned short* __restrict__ At,
                 const unsigned short* __restrict__ Bs,
                 const unsigned short* __restrict__ Bt,
                 const float* __restrict__ bias_s,
                 const float* __restrict__ bias_t,
                 const float* __restrict__ x,
                 float* __restrict__ y_out,
                 unsigned short* __restrict__ y_bf,
                 float* __restrict__ ld_out,
                 int moff, int stage) {
  const int K = 4096;
  __shared__ __align__(16) unsigned short lsAs[BM * BK];
  __shared__ __align__(16) unsigned short lsAt[BM * BK];
  __shared__ __align__(16) unsigned short lsS[BN * BK];
  __shared__ __align__(16) unsigned short lsT[BN * BK];
  __shared__ float rowsum[BM];

  const int tid  = threadIdx.x;
  const int wave = tid >> 6;
  const int lane = tid & 63;
  const int quad = lane >> 4;
  const int l15  = lane & 15;
  const int m0 = blockIdx.y * BM;
  const int n0 = blockIdx.x * BN;
  const int wrow = (wave >> 1) * 64;
  const int wcol = (wave & 1) * 64;

  f32x4 accS[4][4] = {};
  f32x4 accT[4][4] = {};

  for (int k0 = 0; k0 < K; k0 += BK) {
    __syncthreads();
#pragma unroll
    for (int i = 0; i < 4; ++i) {
      int s   = (wave * 4 + i) * 64 + lane;
      int row = s >> 3;
      int kg  = (s & 7) ^ (row & 7);
      long go = (long)row * K + k0 + kg * 8;
      async_load16(As + (long)m0 * K + go, &lsAs[(wave * 4 + i) * 512]);
      async_load16(At + (long)m0 * K + go, &lsAt[(wave * 4 + i) * 512]);
      async_load16(Bs + (long)n0 * K + go, &lsS[(wave * 4 + i) * 512]);
      async_load16(Bt + (long)n0 * K + go, &lsT[(wave * 4 + i) * 512]);
    }
    __syncthreads();

#pragma unroll
    for (int ks = 0; ks < 2; ++ks) {
      short8 as[4], at[4], bs[4], bt[4];
      const int kg = ks * 4 + quad;
#pragma unroll
      for (int t = 0; t < 4; ++t) {
        int row = wrow + t * 16 + l15;
        int pa  = row * 8 + (kg ^ (row & 7));
        as[t] = *(const short8*)&lsAs[pa * 8];
        at[t] = *(const short8*)&lsAt[pa * 8];
        int col = wcol + t * 16 + l15;
        int pb  = col * 8 + (kg ^ (col & 7));
        bs[t] = *(const short8*)&lsS[pb * 8];
        bt[t] = *(const short8*)&lsT[pb * 8];
      }
#pragma unroll
      for (int mt = 0; mt < 4; ++mt)
#pragma unroll
        for (int nt = 0; nt < 4; ++nt) {
          accS[mt][nt] = __builtin_amdgcn_mfma_f32_16x16x32_bf16(
              as[mt], bs[nt], accS[mt][nt], 0, 0, 0);
          accT[mt][nt] = __builtin_amdgcn_mfma_f32_16x16x32_bf16(
              at[mt], bt[nt], accT[mt][nt], 0, 0, 0);
        }
    }
  }

  // --- fused coupling epilogue ---
  if (tid < BM) rowsum[tid] = 0.f;
  __syncthreads();

  const int off = stage ? D1 : 0;
  float bvs[4], bvt[4];
#pragma unroll
  for (int nt = 0; nt < 4; ++nt) {
    int col = n0 + wcol + nt * 16 + l15;
    bvs[nt] = bias_s[col];
    bvt[nt] = bias_t[col];
  }
#pragma unroll
  for (int mt = 0; mt < 4; ++mt)
#pragma unroll
    for (int r = 0; r < 4; ++r) {
      long grow = (long)moff + m0 + wrow + mt * 16 + quad * 4 + r;
      float rs = 0.f;
#pragma unroll
      for (int nt = 0; nt < 4; ++nt) {
        int col = n0 + wcol + nt * 16 + l15;
        float sv = tanhf(accS[mt][nt][r] + bvs[nt]);
        rs += sv;
        float t  = accT[mt][nt][r] + bvt[nt];
        float y  = x[grow * (2 * D1) + off + col] * __expf(sv) + t;
        y_out[grow * (2 * D1) + off + col] = y;
        if (y_bf) y_bf[grow * D1 + col] = f2bf(y);
      }
      // reduce rs over the 16 lanes sharing this row (width-16 groups = quads)
#pragma unroll
      for (int o = 8; o > 0; o >>= 1) rs += __shfl_down(rs, o, 16);
      if (l15 == 0) atomicAdd(&rowsum[wrow + mt * 16 + quad * 4 + r], rs);
    }
  __syncthreads();
  if (tid < BM) atomicAdd(&ld_out[moff + m0 + tid], rowsum[tid]);
}

// ---------------------------------------------------------------------------
// Transpose + fp32->bf16 cast: in[R,C] fp32 -> out[C,R] bf16.
// ---------------------------------------------------------------------------
__global__ __launch_bounds__(256)
void transpose_cast(const float* __restrict__ in, unsigned short* __restrict__ out,
                    int R, int C) {
  __shared__ float tile[32][33];
  const int bx = blockIdx.x * 32;
  const int by = blockIdx.y * 32;
  const int tx = threadIdx.x & 31;
  const int ty = threadIdx.x >> 5;
  for (int j = ty; j < 32; j += 8)
    tile[j][tx] = in[(long)(by + j) * C + bx + tx];
  __syncthreads();
  for (int j = ty; j < 32; j += 8)
    out[(long)(bx + j) * R + by + tx] = f2bf(tile[tx][j]);
}

// x (B, 2048) fp32 -> x2 bf16 packed (B, 1024)
__global__ __launch_bounds__(256)
void cast_x2(const float* __restrict__ x, unsigned short* __restrict__ x2b) {
  long i = (long)blockIdx.x * 256 + threadIdx.x;
  long row = i >> 10, col = i & 1023;
  x2b[i] = f2bf(x[row * (2 * D1) + D1 + col]);
}

__global__ __launch_bounds__(256)
void zero_f(float* __restrict__ p, int n) {
  int i = blockIdx.x * 256 + threadIdx.x;
  if (i < n) p[i] = 0.f;
}

// ---------------------------------------------------------------------------
extern "C" void kernel_launch(void* const* d_in, const int* in_sizes, int n_in,
                              void* d_out, int out_size, void* d_ws, size_t ws_size,
                              hipStream_t stream) {
  const float* x     = (const float*)d_in[0];
  const float* s1_W1 = (const float*)d_in[1];
  const float* s1_b1 = (const float*)d_in[2];
  const float* s1_W2 = (const float*)d_in[3];
  const float* s1_b2 = (const float*)d_in[4];
  const float* t1_W1 = (const float*)d_in[5];
  const float* t1_b1 = (const float*)d_in[6];
  const float* t1_W2 = (const float*)d_in[7];
  const float* t1_b2 = (const float*)d_in[8];
  const float* s2_W1 = (const float*)d_in[9];
  const float* s2_b1 = (const float*)d_in[10];
  const float* s2_W2 = (const float*)d_in[11];
  const float* s2_b2 = (const float*)d_in[12];
  const float* t2_W1 = (const float*)d_in[13];
  const float* t2_b1 = (const float*)d_in[14];
  const float* t2_W2 = (const float*)d_in[15];
  const float* t2_b2 = (const float*)d_in[16];

  const size_t MB = 1024UL * 1024UL;
  // ws layout: w1t 4x8MB @0 | w2t 4x8MB @32MB | xyb 16MB @64MB | h_s,h_t @80MB
  int NC = 32;
  {
    const int cand[6] = {1, 2, 4, 8, 16, 32};
    for (int i = 0; i < 6; ++i) {
      size_t need = 80 * MB + (128 * MB) / (size_t)cand[i];
      if (need <= ws_size) { NC = cand[i]; break; }
    }
  }
  const int Mrows = BDIM / NC;

  char* ws = (char*)d_ws;
  unsigned short* w1t[4], * w2t[4];
  for (int i = 0; i < 4; ++i) {
    w1t[i] = (unsigned short*)(ws + (8 * (size_t)i) * MB);
    w2t[i] = (unsigned short*)(ws + (32 + 8 * (size_t)i) * MB);
  }
  unsigned short* xyb = (unsigned short*)(ws + 64 * MB);       // x2 bf16, later y1 bf16
  size_t hbytes = (size_t)Mrows * HDIM * 2;
  unsigned short* h_s = (unsigned short*)(ws + 80 * MB);
  unsigned short* h_t = (unsigned short*)(ws + 80 * MB + hbytes);

  float* y_out  = (float*)d_out;                               // (B, 2048)
  float* ld_out = (float*)d_out + (long)BDIM * (2 * D1);       // (B,)

  // --- prep ---
  zero_f<<<(BDIM + 255) / 256, 256, 0, stream>>>(ld_out, BDIM);
  cast_x2<<<(BDIM * D1) / 256, 256, 0, stream>>>(x, xyb);
  // W1: (1024,4096) -> (4096,1024)
  transpose_cast<<<dim3(HDIM / 32, D1 / 32), 256, 0, stream>>>(s1_W1, w1t[0], D1, HDIM);
  transpose_cast<<<dim3(HDIM / 32, D1 / 32), 256, 0, stream>>>(t1_W1, w1t[1], D1, HDIM);
  transpose_cast<<<dim3(HDIM / 32, D1 / 32), 256, 0, stream>>>(s2_W1, w1t[2], D1, HDIM);
  transpose_cast<<<dim3(HDIM / 32, D1 / 32), 256, 0, stream>>>(t2_W1, w1t[3], D1, HDIM);
  // W2: (4096,1024) -> (1024,4096)
  transpose_cast<<<dim3(D1 / 32, HDIM / 32), 256, 0, stream>>>(s1_W2, w2t[0], HDIM, D1);
  transpose_cast<<<dim3(D1 / 32, HDIM / 32), 256, 0, stream>>>(t1_W2, w2t[1], HDIM, D1);
  transpose_cast<<<dim3(D1 / 32, HDIM / 32), 256, 0, stream>>>(s2_W2, w2t[2], HDIM, D1);
  transpose_cast<<<dim3(D1 / 32, HDIM / 32), 256, 0, stream>>>(t2_W2, w2t[3], HDIM, D1);

  // --- per-chunk pipeline ---
  for (int c = 0; c < NC; ++c) {
    const int moff = c * Mrows;
    unsigned short* xA = xyb + (size_t)moff * D1;  // x2 rows bf16 (stage1) / y1 (stage2)

    // stage 1: h = relu(x2@W1+b1) for s1,t1; then s/t + coupling -> y1
    gemm1_fused<<<dim3(HDIM / BN, Mrows / BM), 256, 0, stream>>>(
        xA, w1t[0], w1t[1], s1_b1, t1_b1, h_s, h_t);
    gemm2_fused<<<dim3(D1 / BN, Mrows / BM), 256, 0, stream>>>(
        h_s, h_t, w2t[0], w2t[1], s1_b2, t1_b2, x, y_out, xyb, ld_out, moff, 0);

    // stage 2: same on y1 (bf16, aliased into xyb rows)
    gemm1_fused<<<dim3(HDIM / BN, Mrows / BM), 256, 0, stream>>>(
        xA, w1t[2], w1t[3], s2_b1, t2_b1, h_s, h_t);
    gemm2_fused<<<dim3(D1 / BN, Mrows / BM), 256, 0, stream>>>(
        h_s, h_t, w2t[2], w2t[3], s2_b2, t2_b2, x, y_out, nullptr, ld_out, moff, 1);
  }
}